// Round 6
// baseline (76.860 us; speedup 1.0000x reference)
//
#include <hip/hip_runtime.h>

#define M_HALF 16384
#define D 128
#define C 64

#define K1_BLOCKS 64
#define K1_THREADS 1024
#define K1_ROWS 256                     // rows per K1 block
#define LDK 65                          // proto_s [k][c] padded leading dim

#define K3_BLOCKS 256
#define K3_ROWS 64                      // rows per K3 block
#define LDX4 33                         // xrows4 padded leading dim (float4)

// ---- K1: LDS prototype accumulation + direct global atomic merge ----------
__global__ __launch_bounds__(K1_THREADS) void k1_proto(
    const float* __restrict__ x, const int* __restrict__ y,
    float* __restrict__ protoSum,   // [D][C] f32, pre-zeroed
    float* __restrict__ cntSum)     // [C]
{
    __shared__ float proto_s[D * LDK];   // [k][c] padded: bank=(k+c)%32
    __shared__ float cnt_s[C];
    __shared__ int   ycls[K1_ROWS];
    const int tid = threadIdx.x;
    const int base = blockIdx.x * K1_ROWS;

    for (int i = tid; i < D * LDK; i += K1_THREADS) proto_s[i] = 0.f;
    if (tid < C) cnt_s[tid] = 0.f;
    if (tid < K1_ROWS) ycls[tid] = y[base + tid];
    __syncthreads();

    // 8192 float4s per block, perfectly coalesced; one float4/thread/iter
    const float4* x4 = (const float4*)(x + (size_t)base * D);
    #pragma unroll
    for (int it = 0; it < (K1_ROWS * D / 4) / K1_THREADS; ++it) {
        const int fidx = it * K1_THREADS + tid;
        const int row  = fidx >> 5;          // 32 float4 per row
        const int k4   = fidx & 31;
        const int cls  = ycls[row];          // 32-lane broadcast
        const float4 v = x4[fidx];
        const int k = k4 * 4;
        atomicAdd(&proto_s[(k + 0) * LDK + cls], v.x);
        atomicAdd(&proto_s[(k + 1) * LDK + cls], v.y);
        atomicAdd(&proto_s[(k + 2) * LDK + cls], v.z);
        atomicAdd(&proto_s[(k + 3) * LDK + cls], v.w);
        if (k4 == 0) atomicAdd(&cnt_s[cls], 1.f);
    }
    __syncthreads();

    // merge: coalesced global atomics, conflict-free LDS reads
    for (int i = tid; i < D * C; i += K1_THREADS) {
        const int k = i >> 6, c = i & 63;
        atomicAdd(&protoSum[i], proto_s[k * LDK + c]);
    }
    if (tid < C) atomicAdd(&cntSum[tid], cnt_s[tid]);
}

// ---- K3: 4x4-register-tile distances + logsumexp + atomic loss ------------
__global__ __launch_bounds__(256, 2) void k3_dist_loss(
    const float* __restrict__ x, const int* __restrict__ y,
    const float* __restrict__ protoSum, const float* __restrict__ cntSum,
    float* __restrict__ out)
{
    __shared__ float4 xrows4[K3_ROWS * LDX4];  // 33.8 KB, [row][k4] padded
    __shared__ float4 pT4[32 * 64];            // 32 KB, [k4][cc][cg]
    __shared__ float  rc_s[C];
    __shared__ float  wsum[4];
    const int tid = threadIdx.x;

    if (tid < C) {                   // finalize counts -> reciprocal
        float s = cntSum[tid];
        if (s < 0.5f) s = 1.f;       // class_counts + (counts < 0.01)
        rc_s[tid] = 1.f / s;
    }
    const int row0 = M_HALF + blockIdx.x * K3_ROWS;
    {   // stage 64 target rows: linear coalesced read, conflict-free write
        const float4* src = (const float4*)(x + (size_t)row0 * D);
        for (int i = tid; i < K3_ROWS * (D / 4); i += 256) {
            const int row = i >> 5, k4 = i & 31;
            xrows4[row * LDX4 + k4] = src[i];
        }
    }
    __syncthreads();                 // rc_s ready before pT staging
    {   // stage prototypes finalized, layout [k4][cc][cg] (bank-spread for cg)
        for (int o = tid; o < 32 * 64; o += 256) {
            const int k4 = o >> 6, cc = (o >> 4) & 3, cg = o & 15;
            const int c  = cg * 4 + cc;
            const float rc = rc_s[c];
            float4 v;
            v.x = protoSum[(k4 * 4 + 0) * C + c] * rc;
            v.y = protoSum[(k4 * 4 + 1) * C + c] * rc;
            v.z = protoSum[(k4 * 4 + 2) * C + c] * rc;
            v.w = protoSum[(k4 * 4 + 3) * C + c] * rc;
            pT4[o] = v;
        }
    }
    __syncthreads();

    const int lane = tid & 63;
    const int wid  = tid >> 6;
    const int cg   = lane & 15;      // class group: classes [cg*4, cg*4+4)
    const int rg   = lane >> 4;      // row group within wave
    const int rbase = wid * 16 + rg * 4;   // wave: 16 rows; thread: 4 rows

    float acc[4][4];
    #pragma unroll
    for (int r = 0; r < 4; ++r)
        #pragma unroll
        for (int cc = 0; cc < 4; ++cc) acc[r][cc] = 0.f;

    #pragma unroll 2
    for (int k4 = 0; k4 < 32; ++k4) {
        float4 pv[4], xv[4];
        #pragma unroll
        for (int cc = 0; cc < 4; ++cc) pv[cc] = pT4[k4 * 64 + cc * 16 + cg];
        #pragma unroll
        for (int r = 0; r < 4; ++r) xv[r] = xrows4[(rbase + r) * LDX4 + k4];
        #pragma unroll
        for (int r = 0; r < 4; ++r) {
            #pragma unroll
            for (int cc = 0; cc < 4; ++cc) {
                float d;
                d = xv[r].x - pv[cc].x; acc[r][cc] = fmaf(d, fabsf(d), acc[r][cc]);
                d = xv[r].y - pv[cc].y; acc[r][cc] = fmaf(d, fabsf(d), acc[r][cc]);
                d = xv[r].z - pv[cc].z; acc[r][cc] = fmaf(d, fabsf(d), acc[r][cc]);
                d = xv[r].w - pv[cc].w; acc[r][cc] = fmaf(d, fabsf(d), acc[r][cc]);
            }
        }
    }

    const float ninv_d = -1.f / (float)D;
    float lsum = 0.f;
    #pragma unroll
    for (int r = 0; r < 4; ++r) {
        float dv0 = acc[r][0] * ninv_d, dv1 = acc[r][1] * ninv_d;
        float dv2 = acc[r][2] * ninv_d, dv3 = acc[r][3] * ninv_d;
        float mx = fmaxf(fmaxf(dv0, dv1), fmaxf(dv2, dv3));
        #pragma unroll
        for (int off = 8; off; off >>= 1) mx = fmaxf(mx, __shfl_xor(mx, off));
        float se = __expf(dv0 - mx) + __expf(dv1 - mx) +
                   __expf(dv2 - mx) + __expf(dv3 - mx);
        #pragma unroll
        for (int off = 8; off; off >>= 1) se += __shfl_xor(se, off);
        const float lse = mx + __logf(se);

        const int yt  = y[row0 + rbase + r];     // uniform within 16-lane group
        const int cct = yt & 3, cgt = yt >> 2;
        const float v01 = (cct & 1) ? dv1 : dv0;
        const float v23 = (cct & 1) ? dv3 : dv2;
        const float val = (cct & 2) ? v23 : v01;
        const float dy  = __shfl(val, (lane & 48) | cgt);  // within rg-group
        lsum += lse - dy;                        // -logp[y], same across group
    }

    // sum the 4 distinct rg-group values (lanes within a group are identical)
    lsum += __shfl_xor(lsum, 16);
    lsum += __shfl_xor(lsum, 32);

    if (lane == 0) wsum[wid] = lsum;
    __syncthreads();
    if (tid == 0) {
        const float tot = (wsum[0] + wsum[1] + wsum[2] + wsum[3]) * (1.f / (float)M_HALF);
        atomicAdd(out, tot);
    }
}

extern "C" void kernel_launch(void* const* d_in, const int* in_sizes, int n_in,
                              void* d_out, int out_size, void* d_ws, size_t ws_size,
                              hipStream_t stream) {
    const float* x = (const float*)d_in[0];   // [32768][128]
    const int*   y = (const int*)d_in[1];     // [32768]
    float* out = (float*)d_out;

    float* ws_f     = (float*)d_ws;
    float* protoSum = ws_f;                   // 8192 floats
    float* cntSum   = protoSum + D * C;       // 64 floats (contiguous w/ protoSum)

    hipMemsetAsync(protoSum, 0, (D * C + C) * sizeof(float), stream);
    hipMemsetAsync(out, 0, sizeof(float), stream);
    k1_proto<<<K1_BLOCKS, K1_THREADS, 0, stream>>>(x, y, protoSum, cntSum);
    k3_dist_loss<<<K3_BLOCKS, 256, 0, stream>>>(x, y, protoSum, cntSum, out);
}